// Round 4
// baseline (12.548 us; speedup 1.0000x reference)
//
#include <hip/hip_runtime.h>

#define BATCH 16384
#define DIM 128

typedef float vf4 __attribute__((ext_vector_type(4)));

__global__ __launch_bounds__(256) void cc_kernel(
    const float* __restrict__ v, const float* __restrict__ e,
    const float* __restrict__ w_vv, const float* __restrict__ w_ev,
    const float* __restrict__ w_ve, const float* __restrict__ w_ee,
    const float* __restrict__ bias_v, const float* __restrict__ bias_e,
    float* __restrict__ v_out, float* __restrict__ e_out)
{
    const int tid = blockIdx.x * blockDim.x + threadIdx.x;
    const int row = tid >> 5;          // 32 lanes per row
    const int sub = tid & 31;
    const int col = sub << 2;          // 4 elements per lane

    const size_t off = (size_t)row * DIM + col;

    const float4 vr = *reinterpret_cast<const float4*>(v + off);
    const float4 er = *reinterpret_cast<const float4*>(e + off);

    const float4 wvv = *reinterpret_cast<const float4*>(w_vv + col);
    const float4 wev = *reinterpret_cast<const float4*>(w_ev + col);
    const float4 wve = *reinterpret_cast<const float4*>(w_ve + col);
    const float4 wee = *reinterpret_cast<const float4*>(w_ee + col);

    // partial dots: dvv = e.w_vv, dev = v.w_ev, dve = e.w_ve, dee = v.w_ee
    float dvv = er.x*wvv.x + er.y*wvv.y + er.z*wvv.z + er.w*wvv.w;
    float dev = vr.x*wev.x + vr.y*wev.y + vr.z*wev.z + vr.w*wev.w;
    float dve = er.x*wve.x + er.y*wve.y + er.z*wve.z + er.w*wve.w;
    float dee = vr.x*wee.x + vr.y*wee.y + vr.z*wee.z + vr.w*wee.w;

    // butterfly reduce across the 32-lane group
    #pragma unroll
    for (int m = 1; m < 32; m <<= 1) {
        dvv += __shfl_xor(dvv, m, 64);
        dev += __shfl_xor(dev, m, 64);
        dve += __shfl_xor(dve, m, 64);
        dee += __shfl_xor(dee, m, 64);
    }

    const float4 bvr = *reinterpret_cast<const float4*>(bias_v + col);
    const float4 ber = *reinterpret_cast<const float4*>(bias_e + col);

    vf4 vo, eo;
    vo.x = vr.x*dvv + er.x*dev + bvr.x;
    vo.y = vr.y*dvv + er.y*dev + bvr.y;
    vo.z = vr.z*dvv + er.z*dev + bvr.z;
    vo.w = vr.w*dvv + er.w*dev + bvr.w;

    eo.x = vr.x*dve + er.x*dee + ber.x;
    eo.y = vr.y*dve + er.y*dee + ber.y;
    eo.z = vr.z*dve + er.z*dee + ber.z;
    eo.w = vr.w*dve + er.w*dee + ber.w;

    // nontemporal stores: outputs are never re-read by the kernel, keep them
    // from evicting v/e out of per-XCD L2 across graph replays
    __builtin_nontemporal_store(vo, reinterpret_cast<vf4*>(v_out + off));
    __builtin_nontemporal_store(eo, reinterpret_cast<vf4*>(e_out + off));
}

extern "C" void kernel_launch(void* const* d_in, const int* in_sizes, int n_in,
                              void* d_out, int out_size, void* d_ws, size_t ws_size,
                              hipStream_t stream) {
    const float* v    = (const float*)d_in[0];
    const float* e    = (const float*)d_in[1];
    const float* w_vv = (const float*)d_in[2];
    const float* w_ev = (const float*)d_in[3];
    const float* w_ve = (const float*)d_in[4];
    const float* w_ee = (const float*)d_in[5];
    const float* b_v  = (const float*)d_in[6];
    const float* b_e  = (const float*)d_in[7];

    float* v_out = (float*)d_out;
    float* e_out = (float*)d_out + (size_t)BATCH * DIM;

    const int threads = 256;
    const int total   = BATCH * 32;       // 32 lanes per row
    const int blocks  = total / threads;  // 2048

    cc_kernel<<<blocks, threads, 0, stream>>>(v, e, w_vv, w_ev, w_ve, w_ee,
                                              b_v, b_e, v_out, e_out);
}

// Round 5
// 10.766 us; speedup vs baseline: 1.1655x; 1.1655x over previous
//
#include <hip/hip_runtime.h>

#define BATCH 16384
#define DIM 128
#define BLOCKS 512
#define THREADS 256
#define ITERS 4
// rows per pass: BLOCKS*THREADS/32 = 4096; 4096*ITERS = 16384 = BATCH

__global__ __launch_bounds__(256) void cc_kernel(
    const float* __restrict__ v, const float* __restrict__ e,
    const float* __restrict__ w_vv, const float* __restrict__ w_ev,
    const float* __restrict__ w_ve, const float* __restrict__ w_ee,
    const float* __restrict__ bias_v, const float* __restrict__ bias_e,
    float* __restrict__ v_out, float* __restrict__ e_out)
{
    const int tid  = blockIdx.x * blockDim.x + threadIdx.x;
    const int row0 = tid >> 5;          // 32 lanes per row
    const int sub  = tid & 31;
    const int col  = sub << 2;          // 4 elements per lane

    // hoisted: weights + biases loaded once per thread (L1/L2-resident tables)
    const float4 wvv = *reinterpret_cast<const float4*>(w_vv + col);
    const float4 wev = *reinterpret_cast<const float4*>(w_ev + col);
    const float4 wve = *reinterpret_cast<const float4*>(w_ve + col);
    const float4 wee = *reinterpret_cast<const float4*>(w_ee + col);
    const float4 bvr = *reinterpret_cast<const float4*>(bias_v + col);
    const float4 ber = *reinterpret_cast<const float4*>(bias_e + col);

    const size_t stride = (size_t)4096 * DIM;   // rows-per-pass * DIM
    size_t off = (size_t)row0 * DIM + col;

    // prologue: issue first iteration's stream loads
    float4 vr = *reinterpret_cast<const float4*>(v + off);
    float4 er = *reinterpret_cast<const float4*>(e + off);

    #pragma unroll
    for (int it = 0; it < ITERS; ++it) {
        // prefetch next iteration's stream loads before compute
        float4 vn, en;
        const size_t noff = off + stride;
        if (it < ITERS - 1) {
            vn = *reinterpret_cast<const float4*>(v + noff);
            en = *reinterpret_cast<const float4*>(e + noff);
        }

        float dvv = er.x*wvv.x + er.y*wvv.y + er.z*wvv.z + er.w*wvv.w;
        float dev = vr.x*wev.x + vr.y*wev.y + vr.z*wev.z + vr.w*wev.w;
        float dve = er.x*wve.x + er.y*wve.y + er.z*wve.z + er.w*wve.w;
        float dee = vr.x*wee.x + vr.y*wee.y + vr.z*wee.z + vr.w*wee.w;

        #pragma unroll
        for (int m = 1; m < 32; m <<= 1) {
            dvv += __shfl_xor(dvv, m, 64);
            dev += __shfl_xor(dev, m, 64);
            dve += __shfl_xor(dve, m, 64);
            dee += __shfl_xor(dee, m, 64);
        }

        float4 vo, eo;
        vo.x = vr.x*dvv + er.x*dev + bvr.x;
        vo.y = vr.y*dvv + er.y*dev + bvr.y;
        vo.z = vr.z*dvv + er.z*dev + bvr.z;
        vo.w = vr.w*dvv + er.w*dev + bvr.w;

        eo.x = vr.x*dve + er.x*dee + ber.x;
        eo.y = vr.y*dve + er.y*dee + ber.y;
        eo.z = vr.z*dve + er.z*dee + ber.z;
        eo.w = vr.w*dve + er.w*dee + ber.w;

        *reinterpret_cast<float4*>(v_out + off) = vo;
        *reinterpret_cast<float4*>(e_out + off) = eo;

        vr = vn; er = en;
        off = noff;
    }
}

extern "C" void kernel_launch(void* const* d_in, const int* in_sizes, int n_in,
                              void* d_out, int out_size, void* d_ws, size_t ws_size,
                              hipStream_t stream) {
    const float* v    = (const float*)d_in[0];
    const float* e    = (const float*)d_in[1];
    const float* w_vv = (const float*)d_in[2];
    const float* w_ev = (const float*)d_in[3];
    const float* w_ve = (const float*)d_in[4];
    const float* w_ee = (const float*)d_in[5];
    const float* b_v  = (const float*)d_in[6];
    const float* b_e  = (const float*)d_in[7];

    float* v_out = (float*)d_out;
    float* e_out = (float*)d_out + (size_t)BATCH * DIM;

    cc_kernel<<<BLOCKS, THREADS, 0, stream>>>(v, e, w_vv, w_ev, w_ve, w_ee,
                                              b_v, b_e, v_out, e_out);
}